// Round 3
// baseline (79.255 us; speedup 1.0000x reference)
//
#include <hip/hip_runtime.h>
#include <hip/hip_bf16.h>
#include <stdint.h>

// MultiDense: out[b,s,:] = values[b,s,:] @ W[lookups[b]] + bias[lookups[b]]
// B=16384, S=4, IN=OUT=128, 64 experts.
//
// R3: occupancy fix with expert-adjacent dispatch (R2 post-mortem: same-expert
// blocks MUST be consecutive blockIdx so W[e] is read once while all readers
// are concurrent; strided readers re-fetch W and thrash L2 -> 3.5x write amp).
// Grid = 64 experts x 8 chunks = 512 blocks of 512 threads (8 waves).
// LDS 36KB -> 4 blocks/CU, 32 waves/CU. launch_bounds(512,8) caps VGPR=64
// (R2 measured this body at 64 VGPR).

#define NDIMS   64
#define IN_DIM  128
#define OUT_DIM 128
#define BATCH   16384
#define SEQ     4
#define NC      8
#define CHUNK   (BATCH / NC)       // 2048
#define THREADS 512
#define NWAVE   8
#define GRP     4                  // samples per wave-group (16 GEMM rows)

using bf16x8 = __attribute__((ext_vector_type(8))) __bf16;
using f32x4  = __attribute__((ext_vector_type(4))) float;

static __device__ inline uint16_t bf16bits(float f) {
    __bf16 h = (__bf16)f;                   // RNE convert
    return __builtin_bit_cast(uint16_t, h);
}

static __device__ inline bf16x8 cvt8(f32x4 v0, f32x4 v1) {
    bf16x8 r;
    r[0] = (__bf16)v0[0]; r[1] = (__bf16)v0[1];
    r[2] = (__bf16)v0[2]; r[3] = (__bf16)v0[3];
    r[4] = (__bf16)v1[0]; r[5] = (__bf16)v1[1];
    r[6] = (__bf16)v1[2]; r[7] = (__bf16)v1[3];
    return r;
}

__global__ __launch_bounds__(THREADS, 8)
void multidense_kernel(const float* __restrict__ values,
                       const float* __restrict__ W,
                       const float* __restrict__ bias,
                       const int*   __restrict__ lookups,
                       float*       __restrict__ out)
{
    // w_lds byte (n*256 + x) holds Wt[n][(x ^ ((n&7)<<4)) / 2]  (bf16 pairs)
    __shared__ __align__(16) unsigned char w_lds[OUT_DIM * IN_DIM * 2];  // 32 KiB
    __shared__ unsigned short list[CHUNK];                               // 4 KiB
    __shared__ int nm_sh;

    const int tid = threadIdx.x;
    const int e   = blockIdx.x >> 3;        // 8 consecutive blocks share expert e
    const int c   = blockIdx.x & (NC - 1);  // chunk 0..7

    if (tid == 0) nm_sh = 0;
    __syncthreads();

    // ---- Stage W[e]^T -> LDS bf16, transposed + swizzled ----
    // o = tid&127 coalesced over global; each thread covers 8 i-quads.
    {
        const float* We = W + (size_t)e * (IN_DIM * OUT_DIM);
        const int o   = tid & 127;
        const int ih  = tid >> 7;            // 0..3
        const int rot = (o >> 3) & 7;
        const int swz = (o & 7) << 4;
        unsigned char* wrow = &w_lds[o * 256];
        #pragma unroll 4
        for (int qq = 0; qq < 8; ++qq) {
            int q  = ih * 8 + ((qq + rot) & 7);   // quad 0..31
            int i0 = q * 4;
            float f0 = We[(i0 + 0) * OUT_DIM + o];
            float f1 = We[(i0 + 1) * OUT_DIM + o];
            float f2 = We[(i0 + 2) * OUT_DIM + o];
            float f3 = We[(i0 + 3) * OUT_DIM + o];
            uint32_t lo = (uint32_t)bf16bits(f0) | ((uint32_t)bf16bits(f1) << 16);
            uint32_t hi = (uint32_t)bf16bits(f2) | ((uint32_t)bf16bits(f3) << 16);
            uint64_t pk = (uint64_t)lo | ((uint64_t)hi << 32);
            *(uint64_t*)(wrow + ((i0 * 2) ^ swz)) = pk;
        }
    }

    // ---- Scan this chunk of lookups for expert e ----
    {
        const int cbase = c * CHUNK;
        #pragma unroll
        for (int t = 0; t < CHUNK / THREADS; ++t) {
            int idx = cbase + t * THREADS + tid;
            if (lookups[idx] == e) {
                int p = atomicAdd(&nm_sh, 1);
                list[p] = (unsigned short)idx;
            }
        }
    }
    __syncthreads();

    const int nm = nm_sh;
    if (nm == 0) return;

    const int lane = tid & 63;
    const int wid  = tid >> 6;               // 0..7
    const int l15  = lane & 15;
    const int l4   = lane >> 4;              // 0..3
    const int swzB = (l15 & 7) << 4;         // B-fragment row swizzle

    float bias_c[8];
    #pragma unroll
    for (int nf = 0; nf < 8; ++nf) bias_c[nf] = bias[e * OUT_DIM + nf * 16 + l15];

    // ---- Main loop: each wave takes groups of 4 samples (16 GEMM rows) ----
    for (int grp = wid; grp * GRP < nm; grp += NWAVE) {
        const int sbase = grp * GRP;

        // A fragment: row = l15 (sample sbase+(l15>>2), seq row l15&3), k = ks*32+l4*8+j
        int pos  = sbase + (l15 >> 2);
        int posc = pos < nm ? pos : nm - 1;          // clamp tail (stores masked)
        int b    = (int)list[posc];
        const float* pA = values + (size_t)(b * SEQ + (l15 & 3)) * IN_DIM + l4 * 8;

        f32x4 acc[8];
        #pragma unroll
        for (int nf = 0; nf < 8; ++nf) {
            f32x4 a;
            a[0] = bias_c[nf]; a[1] = bias_c[nf]; a[2] = bias_c[nf]; a[3] = bias_c[nf];
            acc[nf] = a;
        }

        #pragma unroll
        for (int ks = 0; ks < 4; ++ks) {
            f32x4 v0 = *(const f32x4*)(pA + ks * 32);
            f32x4 v1 = *(const f32x4*)(pA + ks * 32 + 4);
            bf16x8 afr = cvt8(v0, v1);
            const int koff = (ks * 64 + l4 * 16) ^ swzB;
            #pragma unroll
            for (int nf = 0; nf < 8; ++nf) {
                const bf16x8 bfr = *(const bf16x8*)(&w_lds[(nf * 16 + l15) * 256 + koff]);
                acc[nf] = __builtin_amdgcn_mfma_f32_16x16x32_bf16(afr, bfr, acc[nf], 0, 0, 0);
            }
        }

        // ---- Store: D layout col = l15, row = l4*4 + r ----
        #pragma unroll
        for (int r = 0; r < 4; ++r) {
            int row  = l4 * 4 + r;
            int pos2 = sbase + (row >> 2);
            if (pos2 < nm) {
                int b2 = (int)list[pos2];
                float* po = out + (size_t)(b2 * SEQ + (row & 3)) * OUT_DIM + l15;
                #pragma unroll
                for (int nf = 0; nf < 8; ++nf) po[nf * 16] = acc[nf][r];
            }
        }
    }
}

extern "C" void kernel_launch(void* const* d_in, const int* in_sizes, int n_in,
                              void* d_out, int out_size, void* d_ws, size_t ws_size,
                              hipStream_t stream) {
    const float* values  = (const float*)d_in[0];
    const float* W       = (const float*)d_in[1];
    const float* bias    = (const float*)d_in[2];
    const int*   lookups = (const int*)d_in[3];
    float* out = (float*)d_out;

    hipLaunchKernelGGL(multidense_kernel, dim3(NDIMS * NC), dim3(THREADS), 0, stream,
                       values, W, bias, lookups, out);
}

// Round 4
// 61.185 us; speedup vs baseline: 1.2953x; 1.2953x over previous
//
#include <hip/hip_runtime.h>
#include <hip/hip_bf16.h>
#include <stdint.h>

// MultiDense: out[b,s,:] = values[b,s,:] @ W[lookups[b]] + bias[lookups[b]]
// B=16384, S=4, IN=OUT=128, 64 experts.
//
// R4: two-kernel design.
//  K1 (prep, 64 blocks): (a) convert W[e] fp32 -> bf16 into d_ws in the exact
//     per-lane MFMA B-fragment layout; (b) compact lookups into per-expert
//     global lists (one pass, global atomics).
//  K2 (gemm, 1024 blocks x 256): NO LDS, no barriers. Each wave grabs one
//     4-sample group (16 GEMM rows): wave-prefix-sum over the 64 counts
//     (shfl), ballot-search owning expert, A from values (fp32->bf16 in reg),
//     B fragments straight from d_ws (L1/L2-hot), 32x mfma_f32_16x16x32_bf16,
//     strided fp32 stores. 4096 waves == whole problem resident at once.
//
// R2 lesson: same-expert readers must be concurrent (here W is 2MB bf16 total,
// L2-resident). R3 lesson: don't cap VGPR below need — (256,4) caps at 128,
// body needs ~100.

#define NDIMS   64
#define IN_DIM  128
#define OUT_DIM 128
#define BATCH   16384
#define SEQ     4
#define LISTCAP 1024              // mean 256, sd 16 -> 48 sd of headroom

// d_ws layout (bytes):
//   [0,      256)    cnt[64]  (int32, memset to 0 each call)
//   [1024,   132096) lists: 64 experts x LISTCAP x uint16
//   [262144, 2359296) W bf16 fragment layout: 64 x 8192 x ushort
#define WS_LISTS_OFF  1024
#define WS_WBF16_OFF  262144

using bf16x8 = __attribute__((ext_vector_type(8))) __bf16;
using f32x4  = __attribute__((ext_vector_type(4))) float;

static __device__ inline uint16_t bf16bits(float f) {
    __bf16 h = (__bf16)f;                   // RNE convert
    return __builtin_bit_cast(uint16_t, h);
}

static __device__ inline bf16x8 cvt8(f32x4 v0, f32x4 v1) {
    bf16x8 r;
    r[0] = (__bf16)v0[0]; r[1] = (__bf16)v0[1];
    r[2] = (__bf16)v0[2]; r[3] = (__bf16)v0[3];
    r[4] = (__bf16)v1[0]; r[5] = (__bf16)v1[1];
    r[6] = (__bf16)v1[2]; r[7] = (__bf16)v1[3];
    return r;
}

// ---- K1: prep. Block e: convert W[e] -> bf16 fragment layout; also scan
// lookup chunk [e*256,(e+1)*256) into global per-expert lists.
__global__ __launch_bounds__(256)
void prep_kernel(const float* __restrict__ W,
                 const int*   __restrict__ lookups,
                 int*            cnt,
                 unsigned short* lists,
                 unsigned short* wsW)
{
    const int e   = blockIdx.x;
    const int tid = threadIdx.x;

    // (a) convert: element idx within expert = (((nf*4+ks)*16+l15)*4+l4)*8+j
    //     holds Wt[o][k] = W[k][o], o = nf*16+l15, k = ks*32+l4*8+j.
    const float* We = W + (size_t)e * (IN_DIM * OUT_DIM);
    unsigned short* wo = wsW + (size_t)e * (IN_DIM * OUT_DIM);
    #pragma unroll
    for (int it = 0; it < 8; ++it) {
        int chunk = it * 256 + tid;           // 0..2047 (16B chunks)
        int l4  = chunk & 3;
        int l15 = (chunk >> 2) & 15;
        int ks  = (chunk >> 6) & 3;
        int nf  = chunk >> 8;
        int o   = nf * 16 + l15;
        int k0  = ks * 32 + l4 * 8;
        unsigned short r[8];
        #pragma unroll
        for (int j = 0; j < 8; ++j)
            r[j] = bf16bits(We[(k0 + j) * OUT_DIM + o]);
        *(uint64_t*)(wo + chunk * 8)     = *(const uint64_t*)&r[0];
        *(uint64_t*)(wo + chunk * 8 + 4) = *(const uint64_t*)&r[4];
    }

    // (b) compact lookups (this block's 256-entry slice)
    int i  = e * 256 + tid;
    int e2 = lookups[i];
    int p  = atomicAdd(&cnt[e2], 1);
    if (p < LISTCAP) lists[e2 * LISTCAP + p] = (unsigned short)i;
}

// ---- K2: gemm. One 4-sample group per wave.
__global__ __launch_bounds__(256, 4)
void gemm_kernel(const float* __restrict__ values,
                 const float* __restrict__ bias,
                 const int*   __restrict__ cnt,
                 const unsigned short* __restrict__ lists,
                 const unsigned short* __restrict__ wsW,
                 float*       __restrict__ out)
{
    const int lane = threadIdx.x & 63;
    const int wid  = threadIdx.x >> 6;
    const int l15  = lane & 15;
    const int l4   = lane >> 4;

    // wave-wide exclusive prefix over per-expert group counts (lane = expert)
    int cl   = cnt[lane];
    cl       = cl < LISTCAP ? cl : LISTCAP;
    int grpl = (cl + 3) >> 2;
    int pfx  = grpl;
    #pragma unroll
    for (int d = 1; d < 64; d <<= 1) {
        int t = __shfl_up(pfx, d);
        if (lane >= d) pfx += t;
    }
    const int G    = __shfl(pfx, 63);
    const int excl = pfx - grpl;

    const int nwaves = gridDim.x << 2;
    for (int g = (blockIdx.x << 2) + wid; g < G; g += nwaves) {
        // owning expert: highest lane with excl <= g
        uint64_t m = __ballot(excl <= g);
        int e  = 63 - __builtin_clzll(m);
        int go = g - __shfl(excl, e);
        int ce = __shfl(cl, e);

        // A fragment: row = l15 -> sample go*4+(l15>>2), seq row l15&3
        int pos = go * 4 + (l15 >> 2);
        pos = pos < ce ? pos : ce - 1;                 // clamp tail (stores masked)
        int b = (int)lists[e * LISTCAP + pos];
        const float* pA = values + (size_t)(b * SEQ + (l15 & 3)) * IN_DIM + l4 * 8;

        // B fragment base for this lane
        const unsigned short* wb = wsW + (size_t)e * (IN_DIM * OUT_DIM) + (l15 * 4 + l4) * 8;

        f32x4 acc[8];
        #pragma unroll
        for (int nf = 0; nf < 8; ++nf) {
            float bv = bias[e * OUT_DIM + nf * 16 + l15];
            f32x4 a; a[0] = bv; a[1] = bv; a[2] = bv; a[3] = bv;
            acc[nf] = a;
        }

        #pragma unroll
        for (int ks = 0; ks < 4; ++ks) {
            f32x4 v0 = *(const f32x4*)(pA + ks * 32);
            f32x4 v1 = *(const f32x4*)(pA + ks * 32 + 4);
            bf16x8 afr = cvt8(v0, v1);
            #pragma unroll
            for (int nf = 0; nf < 8; ++nf) {
                const bf16x8 bfr = *(const bf16x8*)(wb + (nf * 4 + ks) * 512);
                acc[nf] = __builtin_amdgcn_mfma_f32_16x16x32_bf16(afr, bfr, acc[nf], 0, 0, 0);
            }
        }

        // store: D layout col = l15, row = l4*4 + r (row -> sample go*4+(row>>2))
        #pragma unroll
        for (int r = 0; r < 4; ++r) {
            int row  = l4 * 4 + r;
            int pos2 = go * 4 + (row >> 2);
            if (pos2 < ce) {
                int b2 = (int)lists[e * LISTCAP + pos2];
                float* po = out + (size_t)(b2 * SEQ + (row & 3)) * OUT_DIM + l15;
                #pragma unroll
                for (int nf = 0; nf < 8; ++nf) po[nf * 16] = acc[nf][r];
            }
        }
    }
}

extern "C" void kernel_launch(void* const* d_in, const int* in_sizes, int n_in,
                              void* d_out, int out_size, void* d_ws, size_t ws_size,
                              hipStream_t stream) {
    const float* values  = (const float*)d_in[0];
    const float* W       = (const float*)d_in[1];
    const float* bias    = (const float*)d_in[2];
    const int*   lookups = (const int*)d_in[3];
    float* out = (float*)d_out;

    int*            cnt   = (int*)d_ws;
    unsigned short* lists = (unsigned short*)((char*)d_ws + WS_LISTS_OFF);
    unsigned short* wsW   = (unsigned short*)((char*)d_ws + WS_WBF16_OFF);

    hipMemsetAsync(cnt, 0, 256, stream);
    hipLaunchKernelGGL(prep_kernel, dim3(NDIMS), dim3(256), 0, stream,
                       W, lookups, cnt, lists, wsW);
    hipLaunchKernelGGL(gemm_kernel, dim3(1024), dim3(256), 0, stream,
                       values, bias, cnt, lists, wsW, out);
}

// Round 5
// 59.744 us; speedup vs baseline: 1.3266x; 1.0241x over previous
//
#include <hip/hip_runtime.h>
#include <hip/hip_bf16.h>
#include <stdint.h>

// MultiDense: out[b,s,:] = values[b,s,:] @ W[lookups[b]] + bias[lookups[b]]
// B=16384, S=4, IN=OUT=128, 64 experts.
//
// R5: R4 minus the hipMemsetAsync — rocprof showed the 256-byte fill costs
// ~40us/dispatch (fillBufferAligned fixed overhead). Replace with a 1-block
// zero kernel (~2us). Prep widened to 256 blocks (expert-quarter each) to cut
// its latency tail. GEMM (the near-roofline part) unchanged:
//   no LDS, no barriers, 1024 blocks x 4 waves; each wave = one 4-sample
//   group (16 GEMM rows x 128 cols) via mfma_f32_16x16x32_bf16; A gathered
//   from values fp32->bf16 in-reg; B fragments from d_ws (bf16, L2-resident).

#define NDIMS   64
#define IN_DIM  128
#define OUT_DIM 128
#define BATCH   16384
#define SEQ     4
#define LISTCAP 1024              // mean 256, sd ~16 -> huge headroom

// d_ws layout (bytes):
//   [0,      256)     cnt[64] (int32, zeroed by zero_kernel each call)
//   [1024,   132096)  lists: 64 x LISTCAP x uint16
//   [262144, 2359296) W bf16 fragment layout: 64 x 8192 x ushort
#define WS_LISTS_OFF  1024
#define WS_WBF16_OFF  262144

using bf16x8 = __attribute__((ext_vector_type(8))) __bf16;
using f32x4  = __attribute__((ext_vector_type(4))) float;

static __device__ inline uint16_t bf16bits(float f) {
    __bf16 h = (__bf16)f;                   // RNE convert
    return __builtin_bit_cast(uint16_t, h);
}

static __device__ inline bf16x8 cvt8(f32x4 v0, f32x4 v1) {
    bf16x8 r;
    r[0] = (__bf16)v0[0]; r[1] = (__bf16)v0[1];
    r[2] = (__bf16)v0[2]; r[3] = (__bf16)v0[3];
    r[4] = (__bf16)v1[0]; r[5] = (__bf16)v1[1];
    r[6] = (__bf16)v1[2]; r[7] = (__bf16)v1[3];
    return r;
}

// ---- K0: zero the 64 counters (hipMemsetAsync's fill kernel cost ~40us!) ----
__global__ void zero_kernel(int* __restrict__ cnt) {
    cnt[threadIdx.x] = 0;
}

// ---- K1: prep. 256 blocks: block b converts quarter (b&3) of expert (b>>2)
//      into bf16 MFMA-B-fragment layout; lanes 0..63 also scan a 64-entry
//      lookup slice into the global per-expert lists.
__global__ __launch_bounds__(256)
void prep_kernel(const float* __restrict__ W,
                 const int*   __restrict__ lookups,
                 int*            cnt,
                 unsigned short* lists,
                 unsigned short* wsW)
{
    const int b   = blockIdx.x;
    const int tid = threadIdx.x;
    const int e   = b >> 2;
    const int q   = b & 3;

    // (a) convert: chunk idx = (((nf*4+ks)*16+l15)*4+l4), 8 bf16 per chunk:
    //     wo[chunk*8 + j] = W[k0+j][o], o = nf*16+l15, k0 = ks*32+l4*8.
    const float* We = W + (size_t)e * (IN_DIM * OUT_DIM);
    unsigned short* wo = wsW + (size_t)e * (IN_DIM * OUT_DIM);
    #pragma unroll
    for (int it = 0; it < 2; ++it) {
        int chunk = q * 512 + it * 256 + tid;  // 0..2047
        int l4  = chunk & 3;
        int l15 = (chunk >> 2) & 15;
        int ks  = (chunk >> 6) & 3;
        int nf  = chunk >> 8;
        int o   = nf * 16 + l15;
        int k0  = ks * 32 + l4 * 8;
        unsigned short r[8];
        #pragma unroll
        for (int j = 0; j < 8; ++j)
            r[j] = bf16bits(We[(k0 + j) * OUT_DIM + o]);
        *(uint64_t*)(wo + chunk * 8)     = *(const uint64_t*)&r[0];
        *(uint64_t*)(wo + chunk * 8 + 4) = *(const uint64_t*)&r[4];
    }

    // (b) compact lookups: this block's 64-entry slice
    if (tid < 64) {
        int i  = b * 64 + tid;
        int e2 = lookups[i];
        int p  = atomicAdd(&cnt[e2], 1);
        if (p < LISTCAP) lists[e2 * LISTCAP + p] = (unsigned short)i;
    }
}

// ---- K2: gemm. One 4-sample group per wave; whole problem resident. ----
__global__ __launch_bounds__(256, 4)
void gemm_kernel(const float* __restrict__ values,
                 const float* __restrict__ bias,
                 const int*   __restrict__ cnt,
                 const unsigned short* __restrict__ lists,
                 const unsigned short* __restrict__ wsW,
                 float*       __restrict__ out)
{
    const int lane = threadIdx.x & 63;
    const int wid  = threadIdx.x >> 6;
    const int l15  = lane & 15;
    const int l4   = lane >> 4;

    // wave-wide exclusive prefix over per-expert group counts (lane = expert)
    int cl   = cnt[lane];
    cl       = cl < LISTCAP ? cl : LISTCAP;
    int grpl = (cl + 3) >> 2;
    int pfx  = grpl;
    #pragma unroll
    for (int d = 1; d < 64; d <<= 1) {
        int t = __shfl_up(pfx, d);
        if (lane >= d) pfx += t;
    }
    const int G    = __shfl(pfx, 63);
    const int excl = pfx - grpl;

    const int nwaves = gridDim.x << 2;
    for (int g = (blockIdx.x << 2) + wid; g < G; g += nwaves) {
        // owning expert: highest lane with excl <= g
        uint64_t m = __ballot(excl <= g);
        int e  = 63 - __builtin_clzll(m);
        int go = g - __shfl(excl, e);
        int ce = __shfl(cl, e);

        // A fragment: row = l15 -> sample go*4+(l15>>2), seq row l15&3
        int pos = go * 4 + (l15 >> 2);
        pos = pos < ce ? pos : ce - 1;                 // clamp tail (stores masked)
        int b = (int)lists[e * LISTCAP + pos];
        const float* pA = values + (size_t)(b * SEQ + (l15 & 3)) * IN_DIM + l4 * 8;

        // B fragment base for this lane
        const unsigned short* wb = wsW + (size_t)e * (IN_DIM * OUT_DIM) + (l15 * 4 + l4) * 8;

        f32x4 acc[8];
        #pragma unroll
        for (int nf = 0; nf < 8; ++nf) {
            float bv = bias[e * OUT_DIM + nf * 16 + l15];
            f32x4 a; a[0] = bv; a[1] = bv; a[2] = bv; a[3] = bv;
            acc[nf] = a;
        }

        #pragma unroll
        for (int ks = 0; ks < 4; ++ks) {
            f32x4 v0 = *(const f32x4*)(pA + ks * 32);
            f32x4 v1 = *(const f32x4*)(pA + ks * 32 + 4);
            bf16x8 afr = cvt8(v0, v1);
            #pragma unroll
            for (int nf = 0; nf < 8; ++nf) {
                const bf16x8 bfr = *(const bf16x8*)(wb + (nf * 4 + ks) * 512);
                acc[nf] = __builtin_amdgcn_mfma_f32_16x16x32_bf16(afr, bfr, acc[nf], 0, 0, 0);
            }
        }

        // store: D layout col = l15, row = l4*4 + r (row -> sample go*4+(row>>2))
        #pragma unroll
        for (int r = 0; r < 4; ++r) {
            int row  = l4 * 4 + r;
            int pos2 = go * 4 + (row >> 2);
            if (pos2 < ce) {
                int b2 = (int)lists[e * LISTCAP + pos2];
                float* po = out + (size_t)(b2 * SEQ + (row & 3)) * OUT_DIM + l15;
                #pragma unroll
                for (int nf = 0; nf < 8; ++nf) po[nf * 16] = acc[nf][r];
            }
        }
    }
}

extern "C" void kernel_launch(void* const* d_in, const int* in_sizes, int n_in,
                              void* d_out, int out_size, void* d_ws, size_t ws_size,
                              hipStream_t stream) {
    const float* values  = (const float*)d_in[0];
    const float* W       = (const float*)d_in[1];
    const float* bias    = (const float*)d_in[2];
    const int*   lookups = (const int*)d_in[3];
    float* out = (float*)d_out;

    int*            cnt   = (int*)d_ws;
    unsigned short* lists = (unsigned short*)((char*)d_ws + WS_LISTS_OFF);
    unsigned short* wsW   = (unsigned short*)((char*)d_ws + WS_WBF16_OFF);

    hipLaunchKernelGGL(zero_kernel, dim3(1), dim3(64), 0, stream, cnt);
    hipLaunchKernelGGL(prep_kernel, dim3(256), dim3(256), 0, stream,
                       W, lookups, cnt, lists, wsW);
    hipLaunchKernelGGL(gemm_kernel, dim3(1024), dim3(256), 0, stream,
                       values, bias, cnt, lists, wsW, out);
}

// Round 6
// 35.599 us; speedup vs baseline: 2.2263x; 1.6783x over previous
//
#include <hip/hip_runtime.h>
#include <hip/hip_bf16.h>
#include <stdint.h>

// MultiDense: out[b,s,:] = values[b,s,:] @ W[lookups[b]] + bias[lookups[b]]
// B=16384, S=4, IN=OUT=128, 64 experts.
//
// R6: kill global-atomic contention + extra kernel nodes (R5 post-mortem:
// zero+prep+gemm measured ~59.7us; gemm models at ~14 -> prep's 16384
// same-line global atomicAdds were the suspect sink).
//  K1 prep (65 blocks x 1024):
//    blocks 0..63: convert W[e] fp32 -> bf16 into d_ws in MFMA B-fragment
//      order (each thread 2x 16B chunks).
//    block 64: compact ALL lookups solo: LDS histogram (LDS atomics only),
//      ranks = atomic return values, dense per-expert lists, then plain
//      stores of cnt[e] -- no zeroing pass, no global atomics.
//  K2 gemm (1024 blocks x 256): unchanged from R5 -- no LDS/barriers; each
//    wave = one 4-sample group (16 rows x 128 cols): wave prefix-sum over
//    cnt, ballot-pick expert, A fp32->bf16 in-reg, B fragments from d_ws,
//    32x mfma_f32_16x16x32_bf16, masked fp32 stores.

#define NDIMS   64
#define IN_DIM  128
#define OUT_DIM 128
#define BATCH   16384
#define SEQ     4
#define LISTCAP 2048

// d_ws layout (bytes):
//   [0, 256)          cnt[64] (int32, plain-stored by prep each call)
//   [4096, 266240)    lists: 64 x LISTCAP x uint16
//   [524288, 2621440) W bf16 fragment layout: 64 x 8192 x ushort
#define WS_LISTS_OFF  4096
#define WS_WBF16_OFF  524288

using bf16x8 = __attribute__((ext_vector_type(8))) __bf16;
using f32x4  = __attribute__((ext_vector_type(4))) float;

static __device__ inline uint16_t bf16bits(float f) {
    __bf16 h = (__bf16)f;                   // RNE convert
    return __builtin_bit_cast(uint16_t, h);
}

static __device__ inline bf16x8 cvt8(f32x4 v0, f32x4 v1) {
    bf16x8 r;
    r[0] = (__bf16)v0[0]; r[1] = (__bf16)v0[1];
    r[2] = (__bf16)v0[2]; r[3] = (__bf16)v0[3];
    r[4] = (__bf16)v1[0]; r[5] = (__bf16)v1[1];
    r[6] = (__bf16)v1[2]; r[7] = (__bf16)v1[3];
    return r;
}

// ---- K1: prep. blocks 0..63 convert W; block 64 compacts lookups. ----
__global__ __launch_bounds__(1024)
void prep_kernel(const float* __restrict__ W,
                 const int*   __restrict__ lookups,
                 int*            cnt,
                 unsigned short* lists,
                 unsigned short* wsW)
{
    const int tid = threadIdx.x;

    if (blockIdx.x < 64) {
        // convert expert e: chunk = (((nf*4+ks)*16+l15)*4+l4); 8 bf16/chunk:
        // wo[chunk*8+j] = W[k0+j][o], o = nf*16+l15, k0 = ks*32+l4*8.
        const int e = blockIdx.x;
        const float* We = W + (size_t)e * (IN_DIM * OUT_DIM);
        unsigned short* wo = wsW + (size_t)e * (IN_DIM * OUT_DIM);
        #pragma unroll
        for (int it = 0; it < 2; ++it) {
            int chunk = it * 1024 + tid;          // 0..2047
            int l4  = chunk & 3;
            int l15 = (chunk >> 2) & 15;
            int ks  = (chunk >> 6) & 3;
            int nf  = chunk >> 8;
            int o   = nf * 16 + l15;
            int k0  = ks * 32 + l4 * 8;
            unsigned short r[8];
            #pragma unroll
            for (int j = 0; j < 8; ++j)
                r[j] = bf16bits(We[(k0 + j) * OUT_DIM + o]);
            *(uint64_t*)(wo + chunk * 8)     = *(const uint64_t*)&r[0];
            *(uint64_t*)(wo + chunk * 8 + 4) = *(const uint64_t*)&r[4];
        }
    } else {
        // solo compaction of all 16384 lookups; LDS atomics only.
        __shared__ int lh[NDIMS];
        if (tid < NDIMS) lh[tid] = 0;
        __syncthreads();

        int ev[16];
        #pragma unroll
        for (int t = 0; t < 16; ++t)
            ev[t] = lookups[t * 1024 + tid];

        int pv[16];
        #pragma unroll
        for (int t = 0; t < 16; ++t)
            pv[t] = atomicAdd(&lh[ev[t]], 1);

        #pragma unroll
        for (int t = 0; t < 16; ++t)
            if (pv[t] < LISTCAP)
                lists[ev[t] * LISTCAP + pv[t]] = (unsigned short)(t * 1024 + tid);

        __syncthreads();
        if (tid < NDIMS) {
            int c = lh[tid];
            cnt[tid] = c < LISTCAP ? c : LISTCAP;
        }
    }
}

// ---- K2: gemm. One 4-sample group per wave; whole problem resident. ----
__global__ __launch_bounds__(256, 4)
void gemm_kernel(const float* __restrict__ values,
                 const float* __restrict__ bias,
                 const int*   __restrict__ cnt,
                 const unsigned short* __restrict__ lists,
                 const unsigned short* __restrict__ wsW,
                 float*       __restrict__ out)
{
    const int lane = threadIdx.x & 63;
    const int wid  = threadIdx.x >> 6;
    const int l15  = lane & 15;
    const int l4   = lane >> 4;

    // wave-wide exclusive prefix over per-expert group counts (lane = expert)
    int cl   = cnt[lane];
    int grpl = (cl + 3) >> 2;
    int pfx  = grpl;
    #pragma unroll
    for (int d = 1; d < 64; d <<= 1) {
        int t = __shfl_up(pfx, d);
        if (lane >= d) pfx += t;
    }
    const int G    = __shfl(pfx, 63);
    const int excl = pfx - grpl;

    const int nwaves = gridDim.x << 2;
    for (int g = (blockIdx.x << 2) + wid; g < G; g += nwaves) {
        // owning expert: highest lane with excl <= g
        uint64_t m = __ballot(excl <= g);
        int e  = 63 - __builtin_clzll(m);
        int go = g - __shfl(excl, e);
        int ce = __shfl(cl, e);

        // A fragment: row = l15 -> sample go*4+(l15>>2), seq row l15&3
        int pos = go * 4 + (l15 >> 2);
        pos = pos < ce ? pos : ce - 1;                 // clamp tail (stores masked)
        int b = (int)lists[e * LISTCAP + pos];
        const float* pA = values + (size_t)(b * SEQ + (l15 & 3)) * IN_DIM + l4 * 8;

        // B fragment base for this lane
        const unsigned short* wb = wsW + (size_t)e * (IN_DIM * OUT_DIM) + (l15 * 4 + l4) * 8;

        f32x4 acc[8];
        #pragma unroll
        for (int nf = 0; nf < 8; ++nf) {
            float bv = bias[e * OUT_DIM + nf * 16 + l15];
            f32x4 a; a[0] = bv; a[1] = bv; a[2] = bv; a[3] = bv;
            acc[nf] = a;
        }

        #pragma unroll
        for (int ks = 0; ks < 4; ++ks) {
            f32x4 v0 = *(const f32x4*)(pA + ks * 32);
            f32x4 v1 = *(const f32x4*)(pA + ks * 32 + 4);
            bf16x8 afr = cvt8(v0, v1);
            #pragma unroll
            for (int nf = 0; nf < 8; ++nf) {
                const bf16x8 bfr = *(const bf16x8*)(wb + (nf * 4 + ks) * 512);
                acc[nf] = __builtin_amdgcn_mfma_f32_16x16x32_bf16(afr, bfr, acc[nf], 0, 0, 0);
            }
        }

        // store: D layout col = l15, row = l4*4 + r (row -> sample go*4+(row>>2))
        #pragma unroll
        for (int r = 0; r < 4; ++r) {
            int row  = l4 * 4 + r;
            int pos2 = go * 4 + (row >> 2);
            if (pos2 < ce) {
                int b2 = (int)lists[e * LISTCAP + pos2];
                float* po = out + (size_t)(b2 * SEQ + (row & 3)) * OUT_DIM + l15;
                #pragma unroll
                for (int nf = 0; nf < 8; ++nf) po[nf * 16] = acc[nf][r];
            }
        }
    }
}

extern "C" void kernel_launch(void* const* d_in, const int* in_sizes, int n_in,
                              void* d_out, int out_size, void* d_ws, size_t ws_size,
                              hipStream_t stream) {
    const float* values  = (const float*)d_in[0];
    const float* W       = (const float*)d_in[1];
    const float* bias    = (const float*)d_in[2];
    const int*   lookups = (const int*)d_in[3];
    float* out = (float*)d_out;

    int*            cnt   = (int*)d_ws;
    unsigned short* lists = (unsigned short*)((char*)d_ws + WS_LISTS_OFF);
    unsigned short* wsW   = (unsigned short*)((char*)d_ws + WS_WBF16_OFF);

    hipLaunchKernelGGL(prep_kernel, dim3(65), dim3(1024), 0, stream,
                       W, lookups, cnt, lists, wsW);
    hipLaunchKernelGGL(gemm_kernel, dim3(1024), dim3(256), 0, stream,
                       values, bias, cnt, lists, wsW, out);
}